// Round 1
// baseline (7327.217 us; speedup 1.0000x reference)
//
#include <hip/hip_runtime.h>
#include <hip/hip_bf16.h>
#include <math.h>

#define D_MODEL 1024
#define N_HEADS 16
#define DH 64
#define BATCH 4
#define SEQ 2048

// ---------------------------------------------------------------------------
// Kernel 1: fused QKV projection.  out = x @ W^T + b  for W in {Wq,Wk,Wv}.
// Output layout: [B, H, T, dh]  (head-major so attention reads are contiguous)
// Classic 64x64 tile fp32 SGEMM, 16-wide K panels, 4x4 register tile/thread.
// ---------------------------------------------------------------------------
#define TILE 64
#define KT 16

__global__ __launch_bounds__(256) void qkv_gemm(
    const float* __restrict__ x,
    const float* __restrict__ Wq, const float* __restrict__ bq,
    const float* __restrict__ Wk, const float* __restrict__ bk,
    const float* __restrict__ Wv, const float* __restrict__ bv,
    float* __restrict__ qws, float* __restrict__ kws, float* __restrict__ vws)
{
    const int z = blockIdx.z;
    const float* __restrict__ W    = (z == 0) ? Wq : (z == 1) ? Wk : Wv;
    const float* __restrict__ bias = (z == 0) ? bq : (z == 1) ? bk : bv;
    float* __restrict__ dst        = (z == 0) ? qws : (z == 1) ? kws : vws;

    __shared__ float As[KT][TILE + 1];
    __shared__ float Bs[KT][TILE + 1];

    const int tid = threadIdx.x;
    const int tx = tid & 15;        // 0..15 -> 64 cols via 4/thread
    const int ty = tid >> 4;        // 0..15 -> 64 rows via 4/thread
    const int rowBase = blockIdx.y * TILE;   // over M = B*T = 8192
    const int colBase = blockIdx.x * TILE;   // over N = D = 1024

    // cooperative load indices: each thread loads one float4 of A and of B
    const int lr = tid >> 2;          // 0..63 row within tile
    const int lk = (tid & 3) * 4;     // 0,4,8,12 k offset

    float acc[4][4] = {};

    const int K = D_MODEL;
    for (int kt = 0; kt < K; kt += KT) {
        float4 av = *(const float4*)(x + (size_t)(rowBase + lr) * K + kt + lk);
        float4 wv = *(const float4*)(W + (size_t)(colBase + lr) * K + kt + lk);
        __syncthreads();   // previous iteration's reads done
        As[lk + 0][lr] = av.x; As[lk + 1][lr] = av.y;
        As[lk + 2][lr] = av.z; As[lk + 3][lr] = av.w;
        Bs[lk + 0][lr] = wv.x; Bs[lk + 1][lr] = wv.y;
        Bs[lk + 2][lr] = wv.z; Bs[lk + 3][lr] = wv.w;
        __syncthreads();
        #pragma unroll
        for (int k = 0; k < KT; ++k) {
            float a0 = As[k][ty * 4 + 0];
            float a1 = As[k][ty * 4 + 1];
            float a2 = As[k][ty * 4 + 2];
            float a3 = As[k][ty * 4 + 3];
            float b0 = Bs[k][tx * 4 + 0];
            float b1 = Bs[k][tx * 4 + 1];
            float b2 = Bs[k][tx * 4 + 2];
            float b3 = Bs[k][tx * 4 + 3];
            acc[0][0] += a0 * b0; acc[0][1] += a0 * b1; acc[0][2] += a0 * b2; acc[0][3] += a0 * b3;
            acc[1][0] += a1 * b0; acc[1][1] += a1 * b1; acc[1][2] += a1 * b2; acc[1][3] += a1 * b3;
            acc[2][0] += a2 * b0; acc[2][1] += a2 * b1; acc[2][2] += a2 * b2; acc[2][3] += a2 * b3;
            acc[3][0] += a3 * b0; acc[3][1] += a3 * b1; acc[3][2] += a3 * b2; acc[3][3] += a3 * b3;
        }
    }

    // epilogue: add bias, scatter to [B,H,T,dh].  One block covers exactly one
    // 64-wide head column block, so per-row writes are 64 contiguous floats.
    #pragma unroll
    for (int i = 0; i < 4; ++i) {
        const int r = rowBase + ty * 4 + i;
        const int b = r >> 11;            // /SEQ
        const int t = r & (SEQ - 1);
        #pragma unroll
        for (int j = 0; j < 4; ++j) {
            const int c = colBase + tx * 4 + j;
            const int h = c >> 6;         // /DH
            const int d = c & (DH - 1);
            dst[(((size_t)b * N_HEADS + h) * SEQ + t) * DH + d] = acc[i][j] + bias[c];
        }
    }
}

// ---------------------------------------------------------------------------
// Kernel 2: causal attention, online softmax.  One wave (64 lanes) per query
// row; lane i owns output dim i (dh == 64 == wavefront size).  4 waves/block,
// consecutive rows in a block share the same (b,h) -> K/V L1/L2 reuse.
// Writes [B,T,D] directly into d_out.
// ---------------------------------------------------------------------------
__global__ __launch_bounds__(256) void attn_kernel(
    const float* __restrict__ qws, const float* __restrict__ kws,
    const float* __restrict__ vws, float* __restrict__ out)
{
    const int lane = threadIdx.x & 63;
    const int wid  = threadIdx.x >> 6;
    const int w    = blockIdx.x * 4 + wid;       // global wave id
    const int t    = w & (SEQ - 1);              // query row
    const int bh   = w >> 11;                    // 0..63
    const size_t base = (size_t)bh * SEQ * DH;

    const float q = qws[base + (size_t)t * DH + lane];
    const float scale = 0.125f;   // 1/sqrt(64)

    float m = -INFINITY, l = 0.f, o = 0.f;

    for (int kc = 0; kc <= t; kc += 64) {
        const int nk = min(64, t - kc + 1);

        // scores: lane j computes s for key kc+j (float4 K reads, Q by shuffle)
        const float4* kp4 = (const float4*)(kws + base + (size_t)(kc + lane) * DH);
        float s = 0.f;
        #pragma unroll
        for (int d4 = 0; d4 < 16; ++d4) {
            float4 kv = kp4[d4];
            s += __shfl(q, 4 * d4 + 0, 64) * kv.x;
            s += __shfl(q, 4 * d4 + 1, 64) * kv.y;
            s += __shfl(q, 4 * d4 + 2, 64) * kv.z;
            s += __shfl(q, 4 * d4 + 3, 64) * kv.w;
        }
        s = (lane < nk) ? s * scale : -INFINITY;

        // chunk max
        float mc = s;
        #pragma unroll
        for (int off = 32; off > 0; off >>= 1)
            mc = fmaxf(mc, __shfl_xor(mc, off, 64));
        const float mnew = fmaxf(m, mc);

        float p = (lane < nk) ? __expf(s - mnew) : 0.f;

        float lc = p;
        #pragma unroll
        for (int off = 32; off > 0; off >>= 1)
            lc += __shfl_xor(lc, off, 64);

        const float alpha = __expf(m - mnew);   // first chunk: exp(-inf)=0
        l = l * alpha + lc;
        o *= alpha;

        // PV: lane owns dim 'lane'; broadcast p_j, coalesced V reads
        const float* vp = vws + base + (size_t)kc * DH + lane;
        for (int j = 0; j < nk; ++j) {
            const float pj = __shfl(p, j, 64);
            o += pj * vp[(size_t)j * DH];
        }
        m = mnew;
    }

    const int b = bh >> 4, h = bh & (N_HEADS - 1);
    out[((size_t)(b * SEQ + t)) * D_MODEL + h * DH + lane] = o / l;
}

// ---------------------------------------------------------------------------
// Kernel 3: residual add + LayerNorm, in place on d_out.  One block per row.
// ---------------------------------------------------------------------------
__global__ __launch_bounds__(256) void resid_ln(
    float* __restrict__ out, const float* __restrict__ x,
    const float* __restrict__ gamma, const float* __restrict__ beta)
{
    const int row = blockIdx.x;
    const int tid = threadIdx.x;
    const int lane = tid & 63;
    const int wid = tid >> 6;

    float4 y  = *(float4*)(out + (size_t)row * D_MODEL + tid * 4);
    float4 xv = *(const float4*)(x + (size_t)row * D_MODEL + tid * 4);
    y.x += xv.x; y.y += xv.y; y.z += xv.z; y.w += xv.w;

    float sum = y.x + y.y + y.z + y.w;
    float sq  = y.x * y.x + y.y * y.y + y.z * y.z + y.w * y.w;
    #pragma unroll
    for (int off = 32; off > 0; off >>= 1) {
        sum += __shfl_xor(sum, off, 64);
        sq  += __shfl_xor(sq, off, 64);
    }

    __shared__ float s1[4], s2[4];
    if (lane == 0) { s1[wid] = sum; s2[wid] = sq; }
    __syncthreads();
    sum = s1[0] + s1[1] + s1[2] + s1[3];
    sq  = s2[0] + s2[1] + s2[2] + s2[3];

    const float mu  = sum * (1.0f / D_MODEL);
    const float var = sq * (1.0f / D_MODEL) - mu * mu;
    const float rs  = rsqrtf(var + 1e-5f);

    float4 g  = *(const float4*)(gamma + tid * 4);
    float4 be = *(const float4*)(beta + tid * 4);
    y.x = (y.x - mu) * rs * g.x + be.x;
    y.y = (y.y - mu) * rs * g.y + be.y;
    y.z = (y.z - mu) * rs * g.z + be.z;
    y.w = (y.w - mu) * rs * g.w + be.w;
    *(float4*)(out + (size_t)row * D_MODEL + tid * 4) = y;
}

// ---------------------------------------------------------------------------
extern "C" void kernel_launch(void* const* d_in, const int* in_sizes, int n_in,
                              void* d_out, int out_size, void* d_ws, size_t ws_size,
                              hipStream_t stream) {
    const float* x     = (const float*)d_in[0];
    const float* Wq    = (const float*)d_in[1];
    const float* bq    = (const float*)d_in[2];
    const float* Wk    = (const float*)d_in[3];
    const float* bk    = (const float*)d_in[4];
    const float* Wv    = (const float*)d_in[5];
    const float* bv    = (const float*)d_in[6];
    const float* gamma = (const float*)d_in[7];
    const float* beta  = (const float*)d_in[8];
    float* out = (float*)d_out;

    // workspace: q, k, v each [B,H,T,dh] fp32 = 32 MB  (total 96 MB)
    const size_t per = (size_t)BATCH * N_HEADS * SEQ * DH;  // 8388608
    float* qws = (float*)d_ws;
    float* kws = qws + per;
    float* vws = kws + per;

    // 1) QKV projection
    dim3 g1(D_MODEL / TILE, (BATCH * SEQ) / TILE, 3);   // (16, 128, 3)
    qkv_gemm<<<g1, 256, 0, stream>>>(x, Wq, bq, Wk, bk, Wv, bv, qws, kws, vws);

    // 2) causal attention -> d_out ([B,T,D])
    const int nwaves = BATCH * N_HEADS * SEQ;           // 131072
    attn_kernel<<<nwaves / 4, 256, 0, stream>>>(qws, kws, vws, out);

    // 3) residual + layernorm, in place
    resid_ln<<<BATCH * SEQ, 256, 0, stream>>>(out, x, gamma, beta);
}

// Round 14
// 454.541 us; speedup vs baseline: 16.1200x; 16.1200x over previous
//
#include <hip/hip_runtime.h>
#include <math.h>

#define D_MODEL 1024
#define N_HEADS 16
#define DH 64
#define BATCH 4
#define SEQ 2048

typedef short  s16x8 __attribute__((ext_vector_type(8)));   // 8 bf16 payloads
typedef __bf16 b16x8 __attribute__((ext_vector_type(8)));   // MFMA operand type
typedef float  f32x4 __attribute__((ext_vector_type(4)));

__device__ __forceinline__ f32x4 mfma16(s16x8 a, s16x8 b, f32x4 c) {
    return __builtin_amdgcn_mfma_f32_16x16x32_bf16(
        __builtin_bit_cast(b16x8, a), __builtin_bit_cast(b16x8, b), c, 0, 0, 0);
}

// fp32 -> bf16 bits, RNE
__device__ __forceinline__ unsigned short f2bf(float f) {
    unsigned u = __float_as_uint(f);
    u += 0x7FFFu + ((u >> 16) & 1u);
    return (unsigned short)(u >> 16);
}

// ---------------------------------------------------------------------------
// Kernel 0: convert x, Wq, Wk, Wv  fp32 -> bf16 (4 elems / thread)
// ranges (in float4 groups): x 2097152 | Wq 262144 | Wk 262144 | Wv 262144
// ---------------------------------------------------------------------------
__global__ __launch_bounds__(256) void convert_bf16(
    const float* __restrict__ x,  const float* __restrict__ wq,
    const float* __restrict__ wk, const float* __restrict__ wv,
    unsigned short* __restrict__ xb,  unsigned short* __restrict__ wqb,
    unsigned short* __restrict__ wkb, unsigned short* __restrict__ wvb)
{
    size_t i4 = (size_t)blockIdx.x * 256 + threadIdx.x;
    const float* src; unsigned short* dst; size_t o;
    if      (i4 < 2097152)          { src = x;  dst = xb;  o = i4; }
    else if (i4 < 2097152 + 262144) { src = wq; dst = wqb; o = i4 - 2097152; }
    else if (i4 < 2097152 + 524288) { src = wk; dst = wkb; o = i4 - 2097152 - 262144; }
    else                            { src = wv; dst = wvb; o = i4 - 2097152 - 524288; }
    float4 v = ((const float4*)src)[o];
    ushort4 r;
    r.x = f2bf(v.x); r.y = f2bf(v.y); r.z = f2bf(v.z); r.w = f2bf(v.w);
    *(ushort4*)&dst[o * 4] = r;
}

// ---------------------------------------------------------------------------
// Kernel 1: QKV projection, bf16 MFMA.  out = x @ W^T + b.
//   q -> [b,h,t,dh] bf16, pre-scaled by 1/8
//   k -> [b,h,t,dh] bf16
//   v -> [b,h,dh,t] bf16  (transposed so attention PV reads are contiguous)
// Block: 64(M) x 64(N) tile, 4 waves each 16x64, K staged in 64-chunks.
// ---------------------------------------------------------------------------
__global__ __launch_bounds__(256) void qkv_mfma(
    const unsigned short* __restrict__ xb,
    const unsigned short* __restrict__ wqb, const unsigned short* __restrict__ wkb,
    const unsigned short* __restrict__ wvb,
    const float* __restrict__ bq, const float* __restrict__ bk,
    const float* __restrict__ bv,
    unsigned short* __restrict__ qws, unsigned short* __restrict__ kws,
    unsigned short* __restrict__ vws)
{
    const int z = blockIdx.z;
    const unsigned short* __restrict__ W = (z == 0) ? wqb : (z == 1) ? wkb : wvb;
    const float* __restrict__ bias       = (z == 0) ? bq  : (z == 1) ? bk  : bv;

    __shared__ __align__(16) short Xs[64][72];
    __shared__ __align__(16) short Ws[64][72];

    const int tid = threadIdx.x;
    const int lane = tid & 63, w = tid >> 6;
    const int c = lane & 15, g = lane >> 4;
    const int rowBase = blockIdx.y * 64;
    const int colBase = blockIdx.x * 64;
    const int lr = tid >> 3, lc = (tid & 7) * 8;   // staging: lr 0..31, lc 0..56

    f32x4 acc[4];
    #pragma unroll
    for (int t = 0; t < 4; ++t) acc[t] = (f32x4)0.0f;

    for (int kt = 0; kt < D_MODEL; kt += 64) {
        __syncthreads();
        *(s16x8*)&Xs[lr][lc]      = *(const s16x8*)&xb[(size_t)(rowBase + lr) * D_MODEL + kt + lc];
        *(s16x8*)&Xs[lr + 32][lc] = *(const s16x8*)&xb[(size_t)(rowBase + lr + 32) * D_MODEL + kt + lc];
        *(s16x8*)&Ws[lr][lc]      = *(const s16x8*)&W[(size_t)(colBase + lr) * D_MODEL + kt + lc];
        *(s16x8*)&Ws[lr + 32][lc] = *(const s16x8*)&W[(size_t)(colBase + lr + 32) * D_MODEL + kt + lc];
        __syncthreads();

        s16x8 a0 = *(const s16x8*)&Xs[w * 16 + c][g * 8];
        s16x8 a1 = *(const s16x8*)&Xs[w * 16 + c][32 + g * 8];
        #pragma unroll
        for (int t = 0; t < 4; ++t) {
            s16x8 b0 = *(const s16x8*)&Ws[t * 16 + c][g * 8];
            s16x8 b1 = *(const s16x8*)&Ws[t * 16 + c][32 + g * 8];
            acc[t] = mfma16(a0, b0, acc[t]);
            acc[t] = mfma16(a1, b1, acc[t]);
        }
    }

    const float qscale = (z == 0) ? 0.125f : 1.0f;   // 1/sqrt(dh) folded into Q
    #pragma unroll
    for (int t = 0; t < 4; ++t) {
        const int n = colBase + t * 16 + c;          // output feature
        const int h = n >> 6, d = n & 63;
        const float bn = bias[n];
        #pragma unroll
        for (int r = 0; r < 4; ++r) {
            const int m  = rowBase + w * 16 + g * 4 + r;   // token index
            const int b  = m >> 11, tt = m & (SEQ - 1);
            const unsigned short bfv = f2bf((acc[t][r] + bn) * qscale);
            if (z == 2)
                vws[((size_t)(b * N_HEADS + h) * DH + d) * SEQ + tt] = bfv;
            else if (z == 0)
                qws[((size_t)(b * N_HEADS + h) * SEQ + tt) * DH + d] = bfv;
            else
                kws[((size_t)(b * N_HEADS + h) * SEQ + tt) * DH + d] = bfv;
        }
    }
}

// ---------------------------------------------------------------------------
// Kernel 2: causal flash attention, bf16 MFMA.
// Block = one (b,h) x 64 query rows; 4 waves x 16 rows each.
// K chunk [64 keys][64 dh] and V^T chunk [64 dh][64 keys] staged in LDS.
// Online softmax in MFMA D-layout; P redistributed via per-wave LDS tile.
// ---------------------------------------------------------------------------
__global__ __launch_bounds__(256) void attn_mfma(
    const unsigned short* __restrict__ qws, const unsigned short* __restrict__ kws,
    const unsigned short* __restrict__ vws, float* __restrict__ out)
{
    __shared__ __align__(16) short Ks[64][72];
    __shared__ __align__(16) short Vs[64][72];        // V^T: [dh][key]
    __shared__ __align__(16) short Ps[4][16][72];     // per-wave P tile

    const int tid = threadIdx.x, lane = tid & 63, w = tid >> 6;
    const int bh = blockIdx.y;
    const int qb = gridDim.x - 1 - blockIdx.x;        // heavy blocks first
    const int qbase = qb * 64;
    const int b = bh >> 4, h = bh & (N_HEADS - 1);

    const unsigned short* qp = qws + (size_t)bh * SEQ * DH;
    const unsigned short* kp = kws + (size_t)bh * SEQ * DH;
    const unsigned short* vp = vws + (size_t)bh * DH * SEQ;

    const int c = lane & 15, g = lane >> 4;
    const int qlo = qbase + w * 16;                   // this wave's first row
    const int lr = tid >> 3, lc = (tid & 7) * 8;

    // Q fragments (A-operand): row = qlo + c, k = g*8 (+32)
    const s16x8 qa0 = *(const s16x8*)&qp[(size_t)(qlo + c) * DH + g * 8];
    const s16x8 qa1 = *(const s16x8*)&qp[(size_t)(qlo + c) * DH + 32 + g * 8];

    f32x4 O[4];
    #pragma unroll
    for (int t = 0; t < 4; ++t) O[t] = (f32x4)0.0f;
    float mrow[4] = {-1e30f, -1e30f, -1e30f, -1e30f};
    float lrow[4] = {0.f, 0.f, 0.f, 0.f};

    const int nch = qb + 1;
    for (int ch = 0; ch < nch; ++ch) {
        const int kc = ch * 64;
        __syncthreads();
        *(s16x8*)&Ks[lr][lc]      = *(const s16x8*)&kp[(size_t)(kc + lr) * DH + lc];
        *(s16x8*)&Ks[lr + 32][lc] = *(const s16x8*)&kp[(size_t)(kc + lr + 32) * DH + lc];
        *(s16x8*)&Vs[lr][lc]      = *(const s16x8*)&vp[(size_t)lr * SEQ + kc + lc];
        *(s16x8*)&Vs[lr + 32][lc] = *(const s16x8*)&vp[(size_t)(lr + 32) * SEQ + kc + lc];
        __syncthreads();

        // S = Q' K^T  (Q pre-scaled); 4 key-tiles x 2 k-steps
        f32x4 S[4];
        #pragma unroll
        for (int t = 0; t < 4; ++t) {
            S[t] = (f32x4)0.0f;
            s16x8 b0 = *(const s16x8*)&Ks[t * 16 + c][g * 8];
            s16x8 b1 = *(const s16x8*)&Ks[t * 16 + c][32 + g * 8];
            S[t] = mfma16(qa0, b0, S[t]);
            S[t] = mfma16(qa1, b1, S[t]);
        }

        // causal mask: needed whenever this chunk's max key (kc+63) exceeds
        // this wave's MIN query row (qlo).  [bugfix: was qlo+15, which left
        // wave 3's diagonal chunk unmasked]
        if (kc + 63 > qlo) {
            #pragma unroll
            for (int t = 0; t < 4; ++t) {
                const int key = kc + t * 16 + c;
                #pragma unroll
                for (int r = 0; r < 4; ++r)
                    if (key > qlo + g * 4 + r) S[t][r] = -1e30f;
            }
        }

        // online softmax: rows live in (g, r); reduce over the 16 lanes of c
        float p[4][4];
        #pragma unroll
        for (int r = 0; r < 4; ++r) {
            float mx = fmaxf(fmaxf(S[0][r], S[1][r]), fmaxf(S[2][r], S[3][r]));
            #pragma unroll
            for (int off = 1; off < 16; off <<= 1)
                mx = fmaxf(mx, __shfl_xor(mx, off, 64));
            const float mn = fmaxf(mrow[r], mx);
            const float al = __expf(mrow[r] - mn);
            mrow[r] = mn;
            float ls = 0.f;
            #pragma unroll
            for (int t = 0; t < 4; ++t) {
                p[t][r] = __expf(S[t][r] - mn);
                ls += p[t][r];
            }
            #pragma unroll
            for (int off = 1; off < 16; off <<= 1)
                ls += __shfl_xor(ls, off, 64);
            lrow[r] = lrow[r] * al + ls;
            #pragma unroll
            for (int t = 0; t < 4; ++t) O[t][r] *= al;
        }

        // P: D-layout -> LDS -> A-fragment layout (same wave, no barrier)
        #pragma unroll
        for (int t = 0; t < 4; ++t)
            #pragma unroll
            for (int r = 0; r < 4; ++r)
                Ps[w][g * 4 + r][t * 16 + c] = (short)f2bf(p[t][r]);

        s16x8 pa0 = *(const s16x8*)&Ps[w][c][g * 8];
        s16x8 pa1 = *(const s16x8*)&Ps[w][c][32 + g * 8];

        // O += P V : B-operand from V^T rows (contiguous keys)
        #pragma unroll
        for (int t = 0; t < 4; ++t) {
            s16x8 v0 = *(const s16x8*)&Vs[t * 16 + c][g * 8];
            s16x8 v1 = *(const s16x8*)&Vs[t * 16 + c][32 + g * 8];
            O[t] = mfma16(pa0, v0, O[t]);
            O[t] = mfma16(pa1, v1, O[t]);
        }
    }

    // epilogue: normalize, write fp32 [B,T,D]
    #pragma unroll
    for (int r = 0; r < 4; ++r) {
        const float inv = 1.0f / lrow[r];
        const int row = qlo + g * 4 + r;
        #pragma unroll
        for (int t = 0; t < 4; ++t)
            out[((size_t)(b * SEQ + row)) * D_MODEL + h * DH + t * 16 + c] = O[t][r] * inv;
    }
}

// ---------------------------------------------------------------------------
// Kernel 3: residual add + LayerNorm, in place on d_out.  One block per row.
// ---------------------------------------------------------------------------
__global__ __launch_bounds__(256) void resid_ln(
    float* __restrict__ out, const float* __restrict__ x,
    const float* __restrict__ gamma, const float* __restrict__ beta)
{
    const int row = blockIdx.x;
    const int tid = threadIdx.x;
    const int lane = tid & 63;
    const int wid = tid >> 6;

    float4 y  = *(float4*)(out + (size_t)row * D_MODEL + tid * 4);
    float4 xv = *(const float4*)(x + (size_t)row * D_MODEL + tid * 4);
    y.x += xv.x; y.y += xv.y; y.z += xv.z; y.w += xv.w;

    float sum = y.x + y.y + y.z + y.w;
    float sq  = y.x * y.x + y.y * y.y + y.z * y.z + y.w * y.w;
    #pragma unroll
    for (int off = 32; off > 0; off >>= 1) {
        sum += __shfl_xor(sum, off, 64);
        sq  += __shfl_xor(sq, off, 64);
    }

    __shared__ float s1[4], s2[4];
    if (lane == 0) { s1[wid] = sum; s2[wid] = sq; }
    __syncthreads();
    sum = s1[0] + s1[1] + s1[2] + s1[3];
    sq  = s2[0] + s2[1] + s2[2] + s2[3];

    const float mu  = sum * (1.0f / D_MODEL);
    const float var = sq * (1.0f / D_MODEL) - mu * mu;
    const float rs  = rsqrtf(var + 1e-5f);

    float4 gm = *(const float4*)(gamma + tid * 4);
    float4 be = *(const float4*)(beta + tid * 4);
    y.x = (y.x - mu) * rs * gm.x + be.x;
    y.y = (y.y - mu) * rs * gm.y + be.y;
    y.z = (y.z - mu) * rs * gm.z + be.z;
    y.w = (y.w - mu) * rs * gm.w + be.w;
    *(float4*)(out + (size_t)row * D_MODEL + tid * 4) = y;
}

// ---------------------------------------------------------------------------
extern "C" void kernel_launch(void* const* d_in, const int* in_sizes, int n_in,
                              void* d_out, int out_size, void* d_ws, size_t ws_size,
                              hipStream_t stream) {
    const float* x     = (const float*)d_in[0];
    const float* Wq    = (const float*)d_in[1];
    const float* bq    = (const float*)d_in[2];
    const float* Wk    = (const float*)d_in[3];
    const float* bk    = (const float*)d_in[4];
    const float* Wv    = (const float*)d_in[5];
    const float* bv    = (const float*)d_in[6];
    const float* gamma = (const float*)d_in[7];
    const float* beta  = (const float*)d_in[8];
    float* out = (float*)d_out;

    // workspace carve-up (bf16 = 2B each):
    //   xb 16MB | wqb 2MB | wkb 2MB | wvb 2MB | qws 16MB | kws 16MB | vws 16MB
    unsigned short* xb  = (unsigned short*)d_ws;
    unsigned short* wqb = xb  + (size_t)BATCH * SEQ * D_MODEL;
    unsigned short* wkb = wqb + (size_t)D_MODEL * D_MODEL;
    unsigned short* wvb = wkb + (size_t)D_MODEL * D_MODEL;
    unsigned short* qws = wvb + (size_t)D_MODEL * D_MODEL;
    unsigned short* kws = qws + (size_t)BATCH * SEQ * D_MODEL;
    unsigned short* vws = kws + (size_t)BATCH * SEQ * D_MODEL;

    // 0) fp32 -> bf16
    convert_bf16<<<11264, 256, 0, stream>>>(x, Wq, Wk, Wv, xb, wqb, wkb, wvb);

    // 1) QKV projection (MFMA)
    dim3 g1(D_MODEL / 64, (BATCH * SEQ) / 64, 3);    // (16, 128, 3)
    qkv_mfma<<<g1, 256, 0, stream>>>(xb, wqb, wkb, wvb, bq, bk, bv, qws, kws, vws);

    // 2) causal flash attention (MFMA) -> d_out fp32 [B,T,D]
    dim3 g2(SEQ / 64, BATCH * N_HEADS);              // (32, 64)
    attn_mfma<<<g2, 256, 0, stream>>>(qws, kws, vws, out);

    // 3) residual + layernorm, in place
    resid_ln<<<BATCH * SEQ, 256, 0, stream>>>(out, x, gamma, beta);
}

// Round 15
// 419.924 us; speedup vs baseline: 17.4489x; 1.0824x over previous
//
#include <hip/hip_runtime.h>
#include <math.h>

#define D_MODEL 1024
#define N_HEADS 16
#define DH 64
#define BATCH 4
#define SEQ 2048

typedef short  s16x8 __attribute__((ext_vector_type(8)));   // 8 bf16 payloads
typedef __bf16 b16x8 __attribute__((ext_vector_type(8)));   // MFMA operand type
typedef float  f32x4 __attribute__((ext_vector_type(4)));
typedef unsigned int u32;

__device__ __forceinline__ f32x4 mfma16(s16x8 a, s16x8 b, f32x4 c) {
    return __builtin_amdgcn_mfma_f32_16x16x32_bf16(
        __builtin_bit_cast(b16x8, a), __builtin_bit_cast(b16x8, b), c, 0, 0, 0);
}

// fp32 -> bf16 bits, RNE
__device__ __forceinline__ unsigned short f2bf(float f) {
    unsigned u = __float_as_uint(f);
    u += 0x7FFFu + ((u >> 16) & 1u);
    return (unsigned short)(u >> 16);
}

// async global->LDS, 16B per lane.  LDS dest = wave-uniform base + lane*16.
__device__ __forceinline__ void gload_lds16(const unsigned short* g, short* l) {
    __builtin_amdgcn_global_load_lds(
        (const __attribute__((address_space(1))) u32*)g,
        (__attribute__((address_space(3))) u32*)l,
        16, 0, 0);
}

// ---------------------------------------------------------------------------
// Kernel 0: convert x, Wq, Wk, Wv  fp32 -> bf16 (4 elems / thread)
// ---------------------------------------------------------------------------
__global__ __launch_bounds__(256) void convert_bf16(
    const float* __restrict__ x,  const float* __restrict__ wq,
    const float* __restrict__ wk, const float* __restrict__ wv,
    unsigned short* __restrict__ xb,  unsigned short* __restrict__ wqb,
    unsigned short* __restrict__ wkb, unsigned short* __restrict__ wvb)
{
    size_t i4 = (size_t)blockIdx.x * 256 + threadIdx.x;
    const float* src; unsigned short* dst; size_t o;
    if      (i4 < 2097152)          { src = x;  dst = xb;  o = i4; }
    else if (i4 < 2097152 + 262144) { src = wq; dst = wqb; o = i4 - 2097152; }
    else if (i4 < 2097152 + 524288) { src = wk; dst = wkb; o = i4 - 2097152 - 262144; }
    else                            { src = wv; dst = wvb; o = i4 - 2097152 - 524288; }
    float4 v = ((const float4*)src)[o];
    ushort4 r;
    r.x = f2bf(v.x); r.y = f2bf(v.y); r.z = f2bf(v.z); r.w = f2bf(v.w);
    *(ushort4*)&dst[o * 4] = r;
}

// ---------------------------------------------------------------------------
// Kernel 1: QKV projection, bf16 MFMA, m97 structure:
// 128x128 tile, BK=64, global_load_lds w16 staging, 4 waves in 2x2,
// each wave 64x64 output (4x4 fragments of 16x16), acc f32x4[4][4].
//   q -> [b,h,t,dh] bf16, pre-scaled by 1/8
//   k -> [b,h,t,dh] bf16
//   v -> [b,h,dh,t] bf16  (transposed for attention PV reads)
// ---------------------------------------------------------------------------
__global__ __launch_bounds__(256) void qkv_mfma(
    const unsigned short* __restrict__ xb,
    const unsigned short* __restrict__ wqb, const unsigned short* __restrict__ wkb,
    const unsigned short* __restrict__ wvb,
    const float* __restrict__ bq, const float* __restrict__ bk,
    const float* __restrict__ bv,
    unsigned short* __restrict__ qws, unsigned short* __restrict__ kws,
    unsigned short* __restrict__ vws)
{
    const int z = blockIdx.z;
    const unsigned short* __restrict__ W = (z == 0) ? wqb : (z == 1) ? wkb : wvb;
    const float* __restrict__ bias       = (z == 0) ? bq  : (z == 1) ? bk  : bv;

    __shared__ __align__(16) short Xs[128][64];   // linear (gload_lds dest)
    __shared__ __align__(16) short Bs[128][64];

    const int tid = threadIdx.x;
    const int lane = tid & 63, w = tid >> 6;
    const int wr = w >> 1, wc = w & 1;            // 2x2 wave grid
    const int c = lane & 15, g = lane >> 4;
    const int rowBase = blockIdx.y * 128;
    const int colBase = blockIdx.x * 128;

    // staging source: lane -> row offset (lane>>3), col (lane&7)*8  (=> lane*16B in LDS)
    const int srow = lane >> 3, scol = (lane & 7) * 8;

    f32x4 acc[4][4];
    #pragma unroll
    for (int m = 0; m < 4; ++m)
        #pragma unroll
        for (int n = 0; n < 4; ++n) acc[m][n] = (f32x4)0.0f;

    for (int kt = 0; kt < D_MODEL; kt += 64) {
        __syncthreads();   // all waves done reading previous tile
        #pragma unroll
        for (int j = 0; j < 4; ++j) {
            const int r = j * 32 + w * 8;         // wave-uniform row group
            gload_lds16(&xb[(size_t)(rowBase + r + srow) * D_MODEL + kt + scol], &Xs[r][0]);
            gload_lds16(&W [(size_t)(colBase + r + srow) * D_MODEL + kt + scol], &Bs[r][0]);
        }
        __syncthreads();   // compiler drains vmcnt before s_barrier -> tile ready

        #pragma unroll
        for (int half = 0; half < 2; ++half) {
            s16x8 a[4], b[4];
            #pragma unroll
            for (int m = 0; m < 4; ++m)
                a[m] = *(const s16x8*)&Xs[wr * 64 + m * 16 + c][half * 32 + g * 8];
            #pragma unroll
            for (int n = 0; n < 4; ++n)
                b[n] = *(const s16x8*)&Bs[wc * 64 + n * 16 + c][half * 32 + g * 8];
            #pragma unroll
            for (int m = 0; m < 4; ++m)
                #pragma unroll
                for (int n = 0; n < 4; ++n)
                    acc[m][n] = mfma16(a[m], b[n], acc[m][n]);
        }
    }

    const float qscale = (z == 0) ? 0.125f : 1.0f;   // 1/sqrt(dh) folded into Q
    #pragma unroll
    for (int n = 0; n < 4; ++n) {
        const int col = colBase + wc * 64 + n * 16 + c;   // output feature
        const int h = col >> 6, d = col & 63;
        const float bn = bias[col];
        #pragma unroll
        for (int m = 0; m < 4; ++m) {
            #pragma unroll
            for (int r = 0; r < 4; ++r) {
                const int row = rowBase + wr * 64 + m * 16 + g * 4 + r;  // token
                const int b  = row >> 11, tt = row & (SEQ - 1);
                const unsigned short bfv = f2bf((acc[m][n][r] + bn) * qscale);
                if (z == 2)
                    vws[((size_t)(b * N_HEADS + h) * DH + d) * SEQ + tt] = bfv;
                else if (z == 0)
                    qws[((size_t)(b * N_HEADS + h) * SEQ + tt) * DH + d] = bfv;
                else
                    kws[((size_t)(b * N_HEADS + h) * SEQ + tt) * DH + d] = bfv;
            }
        }
    }
}

// ---------------------------------------------------------------------------
// Kernel 2: causal flash attention, bf16 MFMA + T14 async-stage split:
// next chunk's K/V prefetched into registers while current chunk computes.
// ---------------------------------------------------------------------------
__global__ __launch_bounds__(256) void attn_mfma(
    const unsigned short* __restrict__ qws, const unsigned short* __restrict__ kws,
    const unsigned short* __restrict__ vws, float* __restrict__ out)
{
    __shared__ __align__(16) short Ks[64][72];
    __shared__ __align__(16) short Vs[64][72];        // V^T: [dh][key]
    __shared__ __align__(16) short Ps[4][16][72];     // per-wave P tile

    const int tid = threadIdx.x, lane = tid & 63, w = tid >> 6;
    const int bh = blockIdx.y;
    const int qb = gridDim.x - 1 - blockIdx.x;        // heavy blocks first
    const int qbase = qb * 64;
    const int b = bh >> 4, h = bh & (N_HEADS - 1);

    const unsigned short* qp = qws + (size_t)bh * SEQ * DH;
    const unsigned short* kp = kws + (size_t)bh * SEQ * DH;
    const unsigned short* vp = vws + (size_t)bh * DH * SEQ;

    const int c = lane & 15, g = lane >> 4;
    const int qlo = qbase + w * 16;                   // this wave's first row
    const int lr = tid >> 3, lc = (tid & 7) * 8;

    // Q fragments (A-operand): row = qlo + c, k = g*8 (+32)
    const s16x8 qa0 = *(const s16x8*)&qp[(size_t)(qlo + c) * DH + g * 8];
    const s16x8 qa1 = *(const s16x8*)&qp[(size_t)(qlo + c) * DH + 32 + g * 8];

    f32x4 O[4];
    #pragma unroll
    for (int t = 0; t < 4; ++t) O[t] = (f32x4)0.0f;
    float mrow[4] = {-1e30f, -1e30f, -1e30f, -1e30f};
    float lrow[4] = {0.f, 0.f, 0.f, 0.f};

    const int nch = qb + 1;

    // prologue: chunk 0 K/V -> regs
    s16x8 kreg0 = *(const s16x8*)&kp[(size_t)lr * DH + lc];
    s16x8 kreg1 = *(const s16x8*)&kp[(size_t)(lr + 32) * DH + lc];
    s16x8 vreg0 = *(const s16x8*)&vp[(size_t)lr * SEQ + lc];
    s16x8 vreg1 = *(const s16x8*)&vp[(size_t)(lr + 32) * SEQ + lc];

    for (int ch = 0; ch < nch; ++ch) {
        const int kc = ch * 64;
        __syncthreads();                  // all waves done reading prev chunk
        *(s16x8*)&Ks[lr][lc]      = kreg0;
        *(s16x8*)&Ks[lr + 32][lc] = kreg1;
        *(s16x8*)&Vs[lr][lc]      = vreg0;
        *(s16x8*)&Vs[lr + 32][lc] = vreg1;
        __syncthreads();                  // chunk ch visible

        // T14: prefetch chunk ch+1 (latency hides under this chunk's compute)
        if (ch + 1 < nch) {
            const int kn = kc + 64;
            kreg0 = *(const s16x8*)&kp[(size_t)(kn + lr) * DH + lc];
            kreg1 = *(const s16x8*)&kp[(size_t)(kn + lr + 32) * DH + lc];
            vreg0 = *(const s16x8*)&vp[(size_t)lr * SEQ + kn + lc];
            vreg1 = *(const s16x8*)&vp[(size_t)(lr + 32) * SEQ + kn + lc];
        }

        // S = Q' K^T  (Q pre-scaled); 4 key-tiles x 2 k-steps
        f32x4 S[4];
        #pragma unroll
        for (int t = 0; t < 4; ++t) {
            S[t] = (f32x4)0.0f;
            s16x8 b0 = *(const s16x8*)&Ks[t * 16 + c][g * 8];
            s16x8 b1 = *(const s16x8*)&Ks[t * 16 + c][32 + g * 8];
            S[t] = mfma16(qa0, b0, S[t]);
            S[t] = mfma16(qa1, b1, S[t]);
        }

        // causal mask: whenever chunk's max key (kc+63) exceeds wave's MIN row
        if (kc + 63 > qlo) {
            #pragma unroll
            for (int t = 0; t < 4; ++t) {
                const int key = kc + t * 16 + c;
                #pragma unroll
                for (int r = 0; r < 4; ++r)
                    if (key > qlo + g * 4 + r) S[t][r] = -1e30f;
            }
        }

        // online softmax: rows live in (g, r); reduce over the 16 lanes of c
        float p[4][4];
        #pragma unroll
        for (int r = 0; r < 4; ++r) {
            float mx = fmaxf(fmaxf(S[0][r], S[1][r]), fmaxf(S[2][r], S[3][r]));
            #pragma unroll
            for (int off = 1; off < 16; off <<= 1)
                mx = fmaxf(mx, __shfl_xor(mx, off, 64));
            const float mn = fmaxf(mrow[r], mx);
            const float al = __expf(mrow[r] - mn);
            mrow[r] = mn;
            float ls = 0.f;
            #pragma unroll
            for (int t = 0; t < 4; ++t) {
                p[t][r] = __expf(S[t][r] - mn);
                ls += p[t][r];
            }
            #pragma unroll
            for (int off = 1; off < 16; off <<= 1)
                ls += __shfl_xor(ls, off, 64);
            lrow[r] = lrow[r] * al + ls;
            #pragma unroll
            for (int t = 0; t < 4; ++t) O[t][r] *= al;
        }

        // P: D-layout -> LDS -> A-fragment layout (same wave, no barrier)
        #pragma unroll
        for (int t = 0; t < 4; ++t)
            #pragma unroll
            for (int r = 0; r < 4; ++r)
                Ps[w][g * 4 + r][t * 16 + c] = (short)f2bf(p[t][r]);

        s16x8 pa0 = *(const s16x8*)&Ps[w][c][g * 8];
        s16x8 pa1 = *(const s16x8*)&Ps[w][c][32 + g * 8];

        // O += P V : B-operand from V^T rows (contiguous keys)
        #pragma unroll
        for (int t = 0; t < 4; ++t) {
            s16x8 v0 = *(const s16x8*)&Vs[t * 16 + c][g * 8];
            s16x8 v1 = *(const s16x8*)&Vs[t * 16 + c][32 + g * 8];
            O[t] = mfma16(pa0, v0, O[t]);
            O[t] = mfma16(pa1, v1, O[t]);
        }
    }

    // epilogue: normalize, write fp32 [B,T,D]
    #pragma unroll
    for (int r = 0; r < 4; ++r) {
        const float inv = 1.0f / lrow[r];
        const int row = qlo + g * 4 + r;
        #pragma unroll
        for (int t = 0; t < 4; ++t)
            out[((size_t)(b * SEQ + row)) * D_MODEL + h * DH + t * 16 + c] = O[t][r] * inv;
    }
}

// ---------------------------------------------------------------------------
// Kernel 3: residual add + LayerNorm, in place on d_out.  One block per row.
// ---------------------------------------------------------------------------
__global__ __launch_bounds__(256) void resid_ln(
    float* __restrict__ out, const float* __restrict__ x,
    const float* __restrict__ gamma, const float* __restrict__ beta)
{
    const int row = blockIdx.x;
    const int tid = threadIdx.x;
    const int lane = tid & 63;
    const int wid = tid >> 6;

    float4 y  = *(float4*)(out + (size_t)row * D_MODEL + tid * 4);
    float4 xv = *(const float4*)(x + (size_t)row * D_MODEL + tid * 4);
    y.x += xv.x; y.y += xv.y; y.z += xv.z; y.w += xv.w;

    float sum = y.x + y.y + y.z + y.w;
    float sq  = y.x * y.x + y.y * y.y + y.z * y.z + y.w * y.w;
    #pragma unroll
    for (int off = 32; off > 0; off >>= 1) {
        sum += __shfl_xor(sum, off, 64);
        sq  += __shfl_xor(sq, off, 64);
    }

    __shared__ float s1[4], s2[4];
    if (lane == 0) { s1[wid] = sum; s2[wid] = sq; }
    __syncthreads();
    sum = s1[0] + s1[1] + s1[2] + s1[3];
    sq  = s2[0] + s2[1] + s2[2] + s2[3];

    const float mu  = sum * (1.0f / D_MODEL);
    const float var = sq * (1.0f / D_MODEL) - mu * mu;
    const float rs  = rsqrtf(var + 1e-5f);

    float4 gm = *(const float4*)(gamma + tid * 4);
    float4 be = *(const float4*)(beta + tid * 4);
    y.x = (y.x - mu) * rs * gm.x + be.x;
    y.y = (y.y - mu) * rs * gm.y + be.y;
    y.z = (y.z - mu) * rs * gm.z + be.z;
    y.w = (y.w - mu) * rs * gm.w + be.w;
    *(float4*)(out + (size_t)row * D_MODEL + tid * 4) = y;
}

// ---------------------------------------------------------------------------
extern "C" void kernel_launch(void* const* d_in, const int* in_sizes, int n_in,
                              void* d_out, int out_size, void* d_ws, size_t ws_size,
                              hipStream_t stream) {
    const float* x     = (const float*)d_in[0];
    const float* Wq    = (const float*)d_in[1];
    const float* bq    = (const float*)d_in[2];
    const float* Wk    = (const float*)d_in[3];
    const float* bk    = (const float*)d_in[4];
    const float* Wv    = (const float*)d_in[5];
    const float* bv    = (const float*)d_in[6];
    const float* gamma = (const float*)d_in[7];
    const float* beta  = (const float*)d_in[8];
    float* out = (float*)d_out;

    // workspace carve-up (bf16 = 2B each):
    //   xb 16MB | wqb 2MB | wkb 2MB | wvb 2MB | qws 16MB | kws 16MB | vws 16MB
    unsigned short* xb  = (unsigned short*)d_ws;
    unsigned short* wqb = xb  + (size_t)BATCH * SEQ * D_MODEL;
    unsigned short* wkb = wqb + (size_t)D_MODEL * D_MODEL;
    unsigned short* wvb = wkb + (size_t)D_MODEL * D_MODEL;
    unsigned short* qws = wvb + (size_t)D_MODEL * D_MODEL;
    unsigned short* kws = qws + (size_t)BATCH * SEQ * D_MODEL;
    unsigned short* vws = kws + (size_t)BATCH * SEQ * D_MODEL;

    // 0) fp32 -> bf16
    convert_bf16<<<11264, 256, 0, stream>>>(x, Wq, Wk, Wv, xb, wqb, wkb, wvb);

    // 1) QKV projection (MFMA, 128x128 tile + global_load_lds)
    dim3 g1(D_MODEL / 128, (BATCH * SEQ) / 128, 3);   // (8, 64, 3)
    qkv_mfma<<<g1, 256, 0, stream>>>(xb, wqb, wkb, wvb, bq, bk, bv, qws, kws, vws);

    // 2) causal flash attention (MFMA + async prefetch) -> d_out fp32 [B,T,D]
    dim3 g2(SEQ / 64, BATCH * N_HEADS);               // (32, 64)
    attn_mfma<<<g2, 256, 0, stream>>>(qws, kws, vws, out);

    // 3) residual + layernorm, in place
    resid_ln<<<BATCH * SEQ, 256, 0, stream>>>(out, x, gamma, beta);
}